// Round 8
// baseline (228.271 us; speedup 1.0000x reference)
//
#include <hip/hip_runtime.h>
#include <hip/hip_bf16.h>
#include <math.h>

#define DEV __device__ __forceinline__

typedef short bf16x8 __attribute__((ext_vector_type(8)));
typedef float f32x4 __attribute__((ext_vector_type(4)));

static constexpr int D  = 1024;
static constexpr int H  = 16;
static constexpr int HD = 64;
static constexpr int DS = 64;
static constexpr int B  = 2;
static constexpr int L  = 2048;
static constexpr int M  = B * L;   // 4096

// softmax scale * log2(e), folded into q at projection time (exp2-based
// softmax, no max subtraction: scores bounded far below exp2 overflow;
// masked scores (-1e30) give exp2 -> 0 exactly).
static constexpr float QSCALE = 0.18033688011112042f; // 0.125 * log2(e)

DEV unsigned short f2bf(float f) {
  union { float f; unsigned u; } x; x.f = f;
  unsigned r = (x.u + 0x7FFFu + ((x.u >> 16) & 1u)) >> 16;
  return (unsigned short)r;
}

DEV float bf2f(unsigned short s) {
  union { unsigned u; float f; } x; x.u = (unsigned)s << 16; return x.f;
}

DEV unsigned pack2bf(float a, float b) {
  return (unsigned)f2bf(a) | ((unsigned)f2bf(b) << 16);
}

// truncation pack (P only: truncation bias cancels between Sum(p*v) and Sum(p))
DEV unsigned pack2bf_trunc(float a, float b) {
  union { float f; unsigned u; } ua{a}, ub{b};
  return (ua.u >> 16) | (ub.u & 0xffff0000u);
}

// async global->LDS, 16B per lane; LDS dest = wave-uniform base + 16*lane.
DEV void gload_lds16(const void* g, void* l) {
  __builtin_amdgcn_global_load_lds(
      (const __attribute__((address_space(1))) unsigned int*)g,
      (__attribute__((address_space(3))) unsigned int*)l, 16, 0, 0);
}

// ---------------- merged preprocessing ----------------
// blocks [0,1024): W transpose+bf16; [1024,3072): x->bf16; [3072,3088): sq/sk
__global__ __launch_bounds__(256) void prep_kernel(
    const float* __restrict__ Wq, const float* __restrict__ Wk,
    const float* __restrict__ Wv, const float* __restrict__ Wo,
    const float* __restrict__ x, const float* __restrict__ subj,
    const float* __restrict__ Wsq, const float* __restrict__ bsq,
    const float* __restrict__ Wsk, const float* __restrict__ bsk,
    unsigned short* __restrict__ WT4, unsigned short* __restrict__ xb,
    float* __restrict__ sq, float* __restrict__ sk) {
  __shared__ float tile[64][65];
  const int blk = blockIdx.x, t = threadIdx.x;
  if (blk < 1024) {
    const int z = blk >> 8, idx = blk & 255;
    const float* W = z == 0 ? Wq : z == 1 ? Wk : z == 2 ? Wv : Wo;
    unsigned short* dst = WT4 + (size_t)z * D * D;
    const int n0 = (idx & 15) * 64, k0 = (idx >> 4) * 64;
    const int c = t & 63, r4 = t >> 6;
#pragma unroll
    for (int rr = 0; rr < 16; ++rr) {
      int row = r4 + rr * 4;
      tile[row][c] = W[(size_t)(k0 + row) * D + n0 + c];
    }
    __syncthreads();
#pragma unroll
    for (int rr = 0; rr < 16; ++rr) {
      int nrow = r4 + rr * 4;
      dst[(size_t)(n0 + nrow) * D + k0 + c] = f2bf(tile[c][nrow]);
    }
  } else if (blk < 3072) {
    size_t g = (size_t)(blk - 1024) * 256 + t;
    const float4* xf = (const float4*)x;
    float4 a = xf[2 * g], b = xf[2 * g + 1];
    union { unsigned short s[8]; uint4 v; } o;
    o.s[0] = f2bf(a.x); o.s[1] = f2bf(a.y); o.s[2] = f2bf(a.z); o.s[3] = f2bf(a.w);
    o.s[4] = f2bf(b.x); o.s[5] = f2bf(b.y); o.s[6] = f2bf(b.z); o.s[7] = f2bf(b.w);
    ((uint4*)xb)[g] = o.v;
  } else {
    int g = (blk - 3072) * 256 + t;  // [0, 4096)
    int ty = g >> 11, b = (g >> 10) & 1, n = g & 1023;
    const float* W = ty ? Wsk : Wsq;
    const float* bias = ty ? bsk : bsq;
    float s = bias[n];
#pragma unroll 8
    for (int d = 0; d < DS; ++d) s += subj[b * DS + d] * W[d * D + n];
    (ty ? sk : sq)[b * D + n] = s;
  }
}

// ---------------- fused QKV projection GEMM (BK=64) ----------------
// z=0: q = (x@Wq + sq)*QSCALE -> qk[0]; z=1: k = x@Wk + sk -> qk[1]
// z=2: v = x@Wv written directly transposed to vT[B,H,64,L] (fused vtrans).
__global__ __launch_bounds__(256) void proj_kernel(
    const unsigned short* __restrict__ xb, const unsigned short* __restrict__ WT3,
    const float* __restrict__ sq, const float* __restrict__ sk,
    unsigned short* __restrict__ qk, unsigned short* __restrict__ vT) {
  __shared__ __align__(16) unsigned short smem[128 * 136];  // 34.8 KB
  unsigned short* As = smem;             // 128*64 (16 KB)
  unsigned short* Bs = smem + 128 * 64;  // 128*64 (16 KB)
  const int z = blockIdx.z;
  const unsigned short* Wt = WT3 + (size_t)z * D * D;
  const int m0 = blockIdx.y * 128, n0 = blockIdx.x * 128;
  const int t = threadIdx.x, l = t & 63, w = t >> 6;
  const int wm = w >> 1, wn = w & 1;
  const int lm = l & 15, lq = l >> 4;
  const int srow8 = t >> 3;
  const int fsw = ((t & 7) ^ ((t >> 3) & 7)) * 8;
  const int swm = lm & 7;
  f32x4 acc[4][4] = {};
  for (int kt = 0; kt < D / 64; ++kt) {
    const int kb = kt * 64;
#pragma unroll
    for (int c = 0; c < 4; ++c) {
      int row = 32 * c + srow8;
      gload_lds16(&xb[(size_t)(m0 + row) * D + kb + fsw], &As[(32 * c + 8 * w) * 64]);
      gload_lds16(&Wt[(size_t)(n0 + row) * D + kb + fsw], &Bs[(32 * c + 8 * w) * 64]);
    }
    __syncthreads();
#pragma unroll
    for (int kk = 0; kk < 2; ++kk) {
      bf16x8 af[4], bf[4];
#pragma unroll
      for (int i = 0; i < 4; ++i)
        af[i] = *(const bf16x8*)&As[(64 * wm + 16 * i + lm) * 64 + ((kk * 4 + lq) ^ swm) * 8];
#pragma unroll
      for (int j = 0; j < 4; ++j)
        bf[j] = *(const bf16x8*)&Bs[(64 * wn + 16 * j + lm) * 64 + ((kk * 4 + lq) ^ swm) * 8];
#pragma unroll
      for (int i = 0; i < 4; ++i)
#pragma unroll
        for (int j = 0; j < 4; ++j)
          acc[i][j] = __builtin_amdgcn_mfma_f32_16x16x32_bf16(af[i], bf[j], acc[i][j], 0, 0, 0);
    }
    __syncthreads();
  }
  if (z == 2) {
    // transpose epilogue: acc -> smem T[col][row] (stride 136) -> vT
#pragma unroll
    for (int i = 0; i < 4; ++i)
#pragma unroll
      for (int j = 0; j < 4; ++j) {
        int cr = 64 * wn + 16 * j + lm;
        int rr = 64 * wm + 16 * i + 4 * lq;
        uint2 u;
        u.x = pack2bf(acc[i][j][0], acc[i][j][1]);
        u.y = pack2bf(acc[i][j][2], acc[i][j][3]);
        *(uint2*)&smem[cr * 136 + rr] = u;
      }
    __syncthreads();
    const int cr = t >> 1, half = t & 1;
    const int bb = m0 >> 11, l0 = m0 & (L - 1);
    const int gcol = n0 + cr, h = gcol >> 6, hd = gcol & 63;
    size_t dbase = ((size_t)(bb * H + h) * HD + hd) * L + l0 + half * 64;
#pragma unroll
    for (int c = 0; c < 8; ++c) {
      uint4 u = *(const uint4*)&smem[cr * 136 + half * 64 + c * 8];
      *(uint4*)&vT[dbase + c * 8] = u;
    }
  } else {
    unsigned short* dst = qk + (size_t)z * M * D;
    const float* bias = z == 0 ? sq : sk;
    const float post = z == 0 ? QSCALE : 1.0f;
#pragma unroll
    for (int i = 0; i < 4; ++i)
#pragma unroll
      for (int j = 0; j < 4; ++j)
#pragma unroll
        for (int r = 0; r < 4; ++r) {
          int grow = m0 + 64 * wm + 16 * i + lq * 4 + r;
          int gcol = n0 + 64 * wn + 16 * j + lm;
          int bb = grow >> 11, ll = grow & (L - 1);
          float v = (acc[i][j][r] + bias[bb * D + gcol]) * post;
          int h = gcol >> 6, hd = gcol & 63;
          dst[((size_t)(bb * H + h) * L + ll) * HD + hd] = f2bf(v);
        }
  }
}

// ---------------- flash attention, split-K over keys ----------------
// grid: 1024 = 32 bh x 16 qtiles x 2 key-splits, XCD-swizzled (bx&7 = XCD
// slot; 4 bh per slot -> K/V L2-resident). block 256 = 4 waves x 32 q-rows.
// 51.2 KB LDS -> 3 blocks/CU resident (grid was the occupancy limiter at 512).
// No-max exp2 softmax makes key-split partials exact plain sums: each split
// writes unnormalized O^T partial ([qrow][feat] bf16) + per-row lsum (f32);
// reduce_kernel combines.
__global__ __launch_bounds__(256) void attn_kernel(
    const unsigned short* __restrict__ q_hm, const unsigned short* __restrict__ k_hm,
    const unsigned short* __restrict__ vT, const unsigned char* __restrict__ mask,
    unsigned short* __restrict__ opart, float* __restrict__ lsp) {
  __shared__ unsigned short Ksb[2 * 64 * 64];   // [buf][key][feat] swizzled
  __shared__ unsigned short Vtb[2 * 64 * 64];   // [buf][feat][key] swizzled
  __shared__ unsigned short Ps[128 * 72];       // [qrow][key] padded; Qs overlay
  const int bx = blockIdx.x;
  const int rest = bx >> 3;                 // 0..127
  const int bhid = (bx & 7) + 8 * (rest >> 5);  // 0..31
  const int qs = rest & 31;
  const int q0 = (qs >> 1) * 128;
  const int split = qs & 1;
  const int h = bhid & 15, b = bhid >> 4;
  const size_t bh = (size_t)(b * H + h);
  const int slot = ((bhid * 16 + (qs >> 1)) * 2 + split);
  const unsigned short* qp = q_hm + bh * L * HD;
  const unsigned short* kp = k_hm + bh * L * HD;
  const unsigned short* vp = vT + bh * HD * L;
  const int t = threadIdx.x, l = t & 63, w = t >> 6;
  const int lm = l & 15, lq = l >> 4;
  const int fsw = ((t & 7) ^ ((t >> 3) & 7)) * 8;
  const int swm = lm & 7;
  const int srow = t >> 3;
  const int kt0 = split * (L / 128), kt1 = kt0 + L / 128;  // 16 iters

  // stage Q tile (128x64, swizzled) into the Ps region + first K/V tile
  unsigned short* Qs = Ps;
#pragma unroll
  for (int c = 0; c < 4; ++c) {
    int row = 32 * c + srow;
    gload_lds16(&qp[(size_t)(q0 + row) * HD + fsw], &Qs[(32 * c + 8 * w) * 64]);
  }
#pragma unroll
  for (int c = 0; c < 2; ++c) {
    int row = 32 * c + srow;
    gload_lds16(&kp[(size_t)(kt0 * 64 + row) * HD + fsw], &Ksb[(32 * c + 8 * w) * 64]);
    gload_lds16(&vp[(size_t)row * L + kt0 * 64 + fsw], &Vtb[(32 * c + 8 * w) * 64]);
  }
  __syncthreads();
  bf16x8 qf[2][2];
#pragma unroll
  for (int i = 0; i < 2; ++i)
#pragma unroll
    for (int kk = 0; kk < 2; ++kk)
      qf[i][kk] = *(const bf16x8*)&Qs[(w * 32 + 16 * i + lm) * 64 + ((kk * 4 + lq) ^ swm) * 8];
  // no barrier needed before P writes: each wave only overwrites its own rows.

  float lsum[2] = {0.f, 0.f};
  f32x4 ot[4][2] = {};

  for (int kt = kt0; kt < kt1; ++kt) {
    const int cur = kt & 1;
    const unsigned short* Kc = Ksb + cur * (64 * 64);
    const unsigned short* Vc = Vtb + cur * (64 * 64);
    if (kt + 1 < kt1) {
      const int nk0 = (kt + 1) * 64;
      unsigned short* Kd = Ksb + (cur ^ 1) * (64 * 64);
      unsigned short* Vd = Vtb + (cur ^ 1) * (64 * 64);
#pragma unroll
      for (int c = 0; c < 2; ++c) {
        int row = 32 * c + srow;
        gload_lds16(&kp[(size_t)(nk0 + row) * HD + fsw], &Kd[(32 * c + 8 * w) * 64]);
        gload_lds16(&vp[(size_t)row * L + nk0 + fsw], &Vd[(32 * c + 8 * w) * 64]);
      }
    }
    unsigned long long mb = __ballot(mask[b * L + kt * 64 + l] != 0);

    // S^T tiles: st[jt][i], key = 16*jt + 4*lq + r, qrow = w*32 + 16*i + lm
    f32x4 st[4][2];
#pragma unroll
    for (int jt = 0; jt < 4; ++jt) {
      bf16x8 kf[2];
#pragma unroll
      for (int kk = 0; kk < 2; ++kk)
        kf[kk] = *(const bf16x8*)&Kc[(16 * jt + lm) * 64 + ((kk * 4 + lq) ^ swm) * 8];
#pragma unroll
      for (int i = 0; i < 2; ++i) {
        f32x4 a = {};
        a = __builtin_amdgcn_mfma_f32_16x16x32_bf16(kf[0], qf[i][0], a, 0, 0, 0);
        a = __builtin_amdgcn_mfma_f32_16x16x32_bf16(kf[1], qf[i][1], a, 0, 0, 0);
        st[jt][i] = a;
      }
    }
    if (mb) {  // wave-uniform; test mask is all-false so this is skipped
      unsigned mlo = (unsigned)(mb >> (4 * lq));
      unsigned mhi = (unsigned)(mb >> (4 * lq + 32));
#pragma unroll
      for (int jt = 0; jt < 4; ++jt)
#pragma unroll
        for (int i = 0; i < 2; ++i)
#pragma unroll
          for (int r = 0; r < 4; ++r) {
            unsigned bits = jt < 2 ? mlo : mhi;
            if ((bits >> (16 * (jt & 1) + r)) & 1u) st[jt][i][r] = -1e30f;
          }
    }
    // p = exp2(s) raw, accumulate lsum, store P (truncated bf16)
#pragma unroll
    for (int i = 0; i < 2; ++i) {
      float ps = 0.f;
#pragma unroll
      for (int jt = 0; jt < 4; ++jt) {
        f32x4 p;
#pragma unroll
        for (int r = 0; r < 4; ++r) {
          float e = __builtin_amdgcn_exp2f(st[jt][i][r]);
          p[r] = e;
          ps += e;
        }
        uint2 u;
        u.x = pack2bf_trunc(p[0], p[1]);
        u.y = pack2bf_trunc(p[2], p[3]);
        *(uint2*)&Ps[(w * 32 + 16 * i + lm) * 72 + 16 * jt + 4 * lq] = u;
      }
      lsum[i] += ps;
    }
    // O^T += V^T P^T
    bf16x8 pf[2][2];
#pragma unroll
    for (int i = 0; i < 2; ++i)
#pragma unroll
      for (int kk = 0; kk < 2; ++kk)
        pf[i][kk] = *(const bf16x8*)&Ps[(w * 32 + 16 * i + lm) * 72 + kk * 32 + lq * 8];
#pragma unroll
    for (int jf = 0; jf < 4; ++jf) {
      bf16x8 vf[2];
#pragma unroll
      for (int kk = 0; kk < 2; ++kk)
        vf[kk] = *(const bf16x8*)&Vc[(16 * jf + lm) * 64 + ((kk * 4 + lq) ^ swm) * 8];
#pragma unroll
      for (int i = 0; i < 2; ++i) {
        ot[jf][i] = __builtin_amdgcn_mfma_f32_16x16x32_bf16(vf[0], pf[i][0], ot[jf][i], 0, 0, 0);
        ot[jf][i] = __builtin_amdgcn_mfma_f32_16x16x32_bf16(vf[1], pf[i][1], ot[jf][i], 0, 0, 0);
      }
    }
    __syncthreads();
  }

  // partial-sum epilogue: lsum totals per qrow + unnormalized O^T in
  // [qrow][feat] bf16 (layout == ctx row layout; no LDS transpose needed).
  unsigned short* op = opart + (size_t)slot * (128 * 64);
#pragma unroll
  for (int i = 0; i < 2; ++i) {
    float s = lsum[i];
    s += __shfl_xor(s, 16, 64);
    s += __shfl_xor(s, 32, 64);
#pragma unroll
    for (int jf = 0; jf < 4; ++jf) {
      uint2 u;
      u.x = pack2bf(ot[jf][i][0], ot[jf][i][1]);
      u.y = pack2bf(ot[jf][i][2], ot[jf][i][3]);
      *(uint2*)&op[(w * 32 + 16 * i + lm) * 64 + 16 * jf + 4 * lq] = u;
    }
    if (l < 16) lsp[slot * 128 + w * 32 + 16 * i + l] = s;
  }
}

// ---------------- split-K reduce: ctx = (O0+O1)/(l0+l1) ----------------
// grid (16 qt, 32 bh), 256 threads; fully coalesced read+write.
__global__ __launch_bounds__(256) void reduce_kernel(
    const unsigned short* __restrict__ opart, const float* __restrict__ lsp,
    unsigned short* __restrict__ ctx) {
  const int qt = blockIdx.x, bh = blockIdx.y;
  const int t = threadIdx.x, row = t >> 1, half = t & 1;
  const int slot = (bh * 16 + qt) * 2;
  const unsigned short* o0 = opart + (size_t)slot * (128 * 64);
  const unsigned short* o1 = o0 + 128 * 64;
  const float rl = 1.0f / (lsp[slot * 128 + row] + lsp[(slot + 1) * 128 + row]);
  const int b = bh >> 4, h = bh & 15;
  size_t cb = ((size_t)(b * L + qt * 128 + row)) * D + h * 64 + half * 32;
#pragma unroll
  for (int c = 0; c < 4; ++c) {
    int off = row * 64 + half * 32 + c * 8;
    union { uint4 v; unsigned short s[8]; } u0, u1, o;
    u0.v = *(const uint4*)&o0[off];
    u1.v = *(const uint4*)&o1[off];
#pragma unroll
    for (int e = 0; e < 8; e += 2) {
      float a = (bf2f(u0.s[e]) + bf2f(u1.s[e])) * rl;
      float bb2 = (bf2f(u0.s[e + 1]) + bf2f(u1.s[e + 1])) * rl;
      ((unsigned*)&o.v)[e >> 1] = pack2bf(a, bb2);
    }
    *(uint4*)&ctx[cb + c * 8] = o.v;
  }
}

// ---------------- output projection GEMM (BK=64): out = ctx@Wo + bo ------
__global__ __launch_bounds__(256) void outgemm_kernel(
    const unsigned short* __restrict__ ctx, const unsigned short* __restrict__ WoT,
    const float* __restrict__ bo, float* __restrict__ out) {
  __shared__ unsigned short As[64 * 64];    // 8 KB
  __shared__ unsigned short Bs[128 * 64];   // 16 KB
  const int m0 = blockIdx.y * 64, n0 = blockIdx.x * 128;
  const int t = threadIdx.x, l = t & 63, w = t >> 6;
  const int wm = w >> 1, wn = w & 1;
  const int lm = l & 15, lq = l >> 4;
  const int srow8 = t >> 3;
  const int fsw = ((t & 7) ^ ((t >> 3) & 7)) * 8;
  const int swm = lm & 7;
  f32x4 acc[2][4] = {};
  for (int kt = 0; kt < D / 64; ++kt) {
    const int kb = kt * 64;
#pragma unroll
    for (int c = 0; c < 2; ++c)
      gload_lds16(&ctx[(size_t)(m0 + 32 * c + srow8) * D + kb + fsw],
                  &As[(32 * c + 8 * w) * 64]);
#pragma unroll
    for (int c = 0; c < 4; ++c)
      gload_lds16(&WoT[(size_t)(n0 + 32 * c + srow8) * D + kb + fsw],
                  &Bs[(32 * c + 8 * w) * 64]);
    __syncthreads();
#pragma unroll
    for (int kk = 0; kk < 2; ++kk) {
      bf16x8 af[2], bf[4];
#pragma unroll
      for (int i = 0; i < 2; ++i)
        af[i] = *(const bf16x8*)&As[(32 * wm + 16 * i + lm) * 64 + ((kk * 4 + lq) ^ swm) * 8];
#pragma unroll
      for (int j = 0; j < 4; ++j)
        bf[j] = *(const bf16x8*)&Bs[(64 * wn + 16 * j + lm) * 64 + ((kk * 4 + lq) ^ swm) * 8];
#pragma unroll
      for (int i = 0; i < 2; ++i)
#pragma unroll
        for (int j = 0; j < 4; ++j)
          acc[i][j] = __builtin_amdgcn_mfma_f32_16x16x32_bf16(af[i], bf[j], acc[i][j], 0, 0, 0);
    }
    __syncthreads();
  }
#pragma unroll
  for (int i = 0; i < 2; ++i)
#pragma unroll
    for (int j = 0; j < 4; ++j)
#pragma unroll
      for (int r = 0; r < 4; ++r) {
        int grow = m0 + 32 * wm + 16 * i + lq * 4 + r;
        int gcol = n0 + 64 * wn + 16 * j + lm;
        out[(size_t)grow * D + gcol] = acc[i][j][r] + bo[gcol];
      }
}

extern "C" void kernel_launch(void* const* d_in, const int* in_sizes, int n_in,
                              void* d_out, int out_size, void* d_ws, size_t ws_size,
                              hipStream_t stream) {
  const float* x    = (const float*)d_in[0];
  const float* subj = (const float*)d_in[1];
  const unsigned char* mask = (const unsigned char*)d_in[2];
  const float* Wq = (const float*)d_in[3];
  const float* Wk = (const float*)d_in[4];
  const float* Wv = (const float*)d_in[5];
  const float* Wo = (const float*)d_in[6];
  const float* bo = (const float*)d_in[7];
  const float* Wsq = (const float*)d_in[8];
  const float* bsq = (const float*)d_in[9];
  const float* Wsk = (const float*)d_in[10];
  const float* bsk = (const float*)d_in[11];
  float* out = (float*)d_out;
  char* ws = (char*)d_ws;

  // workspace layout (bytes)
  unsigned short* xb    = (unsigned short*)(ws);                  // 8 MB
  unsigned short* WT4   = (unsigned short*)(ws + (8ull  << 20));  // 8 MB
  unsigned short* qk    = (unsigned short*)(ws + (16ull << 20));  // 16 MB (q,k)
  unsigned short* ctx   = (unsigned short*)(ws + (32ull << 20));  // 8 MB
  unsigned short* vT    = (unsigned short*)(ws + (40ull << 20));  // 8 MB
  float* sq             = (float*)(ws + (48ull << 20));           // 8 KB
  float* sk             = sq + B * D;
  unsigned short* opart = (unsigned short*)(ws + (49ull << 20));  // 16 MB
  float* lsp            = (float*)(ws + (65ull << 20));           // 512 KB

  hipLaunchKernelGGL(prep_kernel, dim3(3088), dim3(256), 0, stream,
                     Wq, Wk, Wv, Wo, x, subj, Wsq, bsq, Wsk, bsk, WT4, xb, sq, sk);
  hipLaunchKernelGGL(proj_kernel, dim3(8, 32, 3), dim3(256), 0, stream,
                     xb, WT4, sq, sk, qk, vT);
  hipLaunchKernelGGL(attn_kernel, dim3(1024), dim3(256), 0, stream,
                     qk, qk + (size_t)M * D, vT, mask, opart, lsp);
  hipLaunchKernelGGL(reduce_kernel, dim3(16, 32), dim3(256), 0, stream,
                     opart, lsp, ctx);
  hipLaunchKernelGGL(outgemm_kernel, dim3(8, 64, 1), dim3(256), 0, stream, ctx,
                     WT4 + 3ull * D * D, bo, out);
}

// Round 9
// 220.543 us; speedup vs baseline: 1.0350x; 1.0350x over previous
//
#include <hip/hip_runtime.h>
#include <hip/hip_bf16.h>
#include <math.h>

#define DEV __device__ __forceinline__

typedef short bf16x8 __attribute__((ext_vector_type(8)));
typedef short bf16x4 __attribute__((ext_vector_type(4)));
typedef float f32x4 __attribute__((ext_vector_type(4)));

#if __has_builtin(__builtin_amdgcn_mfma_f32_16x16x16bf16_1k)
#define HAVE_MFMA16 1
#else
#define HAVE_MFMA16 0
#endif

static constexpr int D  = 1024;
static constexpr int H  = 16;
static constexpr int HD = 64;
static constexpr int DS = 64;
static constexpr int B  = 2;
static constexpr int L  = 2048;
static constexpr int M  = B * L;   // 4096

// softmax scale * log2(e), folded into q at projection time (exp2-based
// softmax, no max subtraction: scores bounded far below exp2 overflow;
// masked scores (-1e30) give exp2 -> 0 exactly).
static constexpr float QSCALE = 0.18033688011112042f; // 0.125 * log2(e)

DEV unsigned short f2bf(float f) {
  union { float f; unsigned u; } x; x.f = f;
  unsigned r = (x.u + 0x7FFFu + ((x.u >> 16) & 1u)) >> 16;
  return (unsigned short)r;
}

DEV unsigned pack2bf(float a, float b) {
  return (unsigned)f2bf(a) | ((unsigned)f2bf(b) << 16);
}

// truncation pack (P only: truncation bias cancels between Sum(p*v) and Sum(p))
DEV unsigned pack2bf_trunc(float a, float b) {
  union { float f; unsigned u; } ua{a}, ub{b};
  return (ua.u >> 16) | (ub.u & 0xffff0000u);
}

// async global->LDS, 16B per lane; LDS dest = wave-uniform base + 16*lane.
DEV void gload_lds16(const void* g, void* l) {
  __builtin_amdgcn_global_load_lds(
      (const __attribute__((address_space(1))) unsigned int*)g,
      (__attribute__((address_space(3))) unsigned int*)l, 16, 0, 0);
}

// ---------------- merged preprocessing ----------------
// blocks [0,1024): W transpose+bf16; [1024,3072): x->bf16; [3072,3088): sq/sk
__global__ __launch_bounds__(256) void prep_kernel(
    const float* __restrict__ Wq, const float* __restrict__ Wk,
    const float* __restrict__ Wv, const float* __restrict__ Wo,
    const float* __restrict__ x, const float* __restrict__ subj,
    const float* __restrict__ Wsq, const float* __restrict__ bsq,
    const float* __restrict__ Wsk, const float* __restrict__ bsk,
    unsigned short* __restrict__ WT4, unsigned short* __restrict__ xb,
    float* __restrict__ sq, float* __restrict__ sk) {
  __shared__ float tile[64][65];
  const int blk = blockIdx.x, t = threadIdx.x;
  if (blk < 1024) {
    const int z = blk >> 8, idx = blk & 255;
    const float* W = z == 0 ? Wq : z == 1 ? Wk : z == 2 ? Wv : Wo;
    unsigned short* dst = WT4 + (size_t)z * D * D;
    const int n0 = (idx & 15) * 64, k0 = (idx >> 4) * 64;
    const int c = t & 63, r4 = t >> 6;
#pragma unroll
    for (int rr = 0; rr < 16; ++rr) {
      int row = r4 + rr * 4;
      tile[row][c] = W[(size_t)(k0 + row) * D + n0 + c];
    }
    __syncthreads();
#pragma unroll
    for (int rr = 0; rr < 16; ++rr) {
      int nrow = r4 + rr * 4;
      dst[(size_t)(n0 + nrow) * D + k0 + c] = f2bf(tile[c][nrow]);
    }
  } else if (blk < 3072) {
    size_t g = (size_t)(blk - 1024) * 256 + t;
    const float4* xf = (const float4*)x;
    float4 a = xf[2 * g], b = xf[2 * g + 1];
    union { unsigned short s[8]; uint4 v; } o;
    o.s[0] = f2bf(a.x); o.s[1] = f2bf(a.y); o.s[2] = f2bf(a.z); o.s[3] = f2bf(a.w);
    o.s[4] = f2bf(b.x); o.s[5] = f2bf(b.y); o.s[6] = f2bf(b.z); o.s[7] = f2bf(b.w);
    ((uint4*)xb)[g] = o.v;
  } else {
    int g = (blk - 3072) * 256 + t;  // [0, 4096)
    int ty = g >> 11, b = (g >> 10) & 1, n = g & 1023;
    const float* W = ty ? Wsk : Wsq;
    const float* bias = ty ? bsk : bsq;
    float s = bias[n];
#pragma unroll 8
    for (int d = 0; d < DS; ++d) s += subj[b * DS + d] * W[d * D + n];
    (ty ? sk : sq)[b * D + n] = s;
  }
}

// ---------------- fused QKV projection GEMM (BK=64) ----------------
// z=0: q = (x@Wq + sq)*QSCALE -> qk[0]; z=1: k = x@Wk + sk -> qk[1]
// z=2: v = x@Wv written directly transposed to vT[B,H,64,L] (fused vtrans).
// q/k epilogue routes through smem (stride 136) for 16B-coalesced stores
// (was 64 scalar 2B global stores per thread).
__global__ __launch_bounds__(256) void proj_kernel(
    const unsigned short* __restrict__ xb, const unsigned short* __restrict__ WT3,
    const float* __restrict__ sq, const float* __restrict__ sk,
    unsigned short* __restrict__ qk, unsigned short* __restrict__ vT) {
  __shared__ __align__(16) unsigned short smem[128 * 136];  // 34.8 KB
  unsigned short* As = smem;             // 128*64 (16 KB)
  unsigned short* Bs = smem + 128 * 64;  // 128*64 (16 KB)
  const int z = blockIdx.z;
  const unsigned short* Wt = WT3 + (size_t)z * D * D;
  const int m0 = blockIdx.y * 128, n0 = blockIdx.x * 128;
  const int t = threadIdx.x, l = t & 63, w = t >> 6;
  const int wm = w >> 1, wn = w & 1;
  const int lm = l & 15, lq = l >> 4;
  const int srow8 = t >> 3;
  const int fsw = ((t & 7) ^ ((t >> 3) & 7)) * 8;
  const int swm = lm & 7;
  f32x4 acc[4][4] = {};
  for (int kt = 0; kt < D / 64; ++kt) {
    const int kb = kt * 64;
#pragma unroll
    for (int c = 0; c < 4; ++c) {
      int row = 32 * c + srow8;
      gload_lds16(&xb[(size_t)(m0 + row) * D + kb + fsw], &As[(32 * c + 8 * w) * 64]);
      gload_lds16(&Wt[(size_t)(n0 + row) * D + kb + fsw], &Bs[(32 * c + 8 * w) * 64]);
    }
    __syncthreads();
#pragma unroll
    for (int kk = 0; kk < 2; ++kk) {
      bf16x8 af[4], bf[4];
#pragma unroll
      for (int i = 0; i < 4; ++i)
        af[i] = *(const bf16x8*)&As[(64 * wm + 16 * i + lm) * 64 + ((kk * 4 + lq) ^ swm) * 8];
#pragma unroll
      for (int j = 0; j < 4; ++j)
        bf[j] = *(const bf16x8*)&Bs[(64 * wn + 16 * j + lm) * 64 + ((kk * 4 + lq) ^ swm) * 8];
#pragma unroll
      for (int i = 0; i < 4; ++i)
#pragma unroll
        for (int j = 0; j < 4; ++j)
          acc[i][j] = __builtin_amdgcn_mfma_f32_16x16x32_bf16(af[i], bf[j], acc[i][j], 0, 0, 0);
    }
    __syncthreads();
  }
  if (z == 2) {
    // transpose epilogue: acc -> smem T[col][row] (stride 136) -> vT
#pragma unroll
    for (int i = 0; i < 4; ++i)
#pragma unroll
      for (int j = 0; j < 4; ++j) {
        int cr = 64 * wn + 16 * j + lm;
        int rr = 64 * wm + 16 * i + 4 * lq;
        uint2 u;
        u.x = pack2bf(acc[i][j][0], acc[i][j][1]);
        u.y = pack2bf(acc[i][j][2], acc[i][j][3]);
        *(uint2*)&smem[cr * 136 + rr] = u;
      }
    __syncthreads();
    const int cr = t >> 1, half = t & 1;
    const int bb = m0 >> 11, l0 = m0 & (L - 1);
    const int gcol = n0 + cr, h = gcol >> 6, hd = gcol & 63;
    size_t dbase = ((size_t)(bb * H + h) * HD + hd) * L + l0 + half * 64;
#pragma unroll
    for (int c = 0; c < 8; ++c) {
      uint4 u = *(const uint4*)&smem[cr * 136 + half * 64 + c * 8];
      *(uint4*)&vT[dbase + c * 8] = u;
    }
  } else {
    unsigned short* dst = qk + (size_t)z * M * D;
    const float* bias = z == 0 ? sq : sk;
    const float post = z == 0 ? QSCALE : 1.0f;
    // stage [row][col] into smem, then fully-coalesced 16B stores
#pragma unroll
    for (int i = 0; i < 4; ++i)
#pragma unroll
      for (int j = 0; j < 4; ++j)
#pragma unroll
        for (int r = 0; r < 4; ++r) {
          int rr = 64 * wm + 16 * i + 4 * lq + r;
          int cc = 64 * wn + 16 * j + lm;
          float v = (acc[i][j][r] + bias[((m0 + rr) >> 11) * D + n0 + cc]) * post;
          smem[rr * 136 + cc] = f2bf(v);
        }
    __syncthreads();
    const int row = t >> 1, half = t & 1;
    const int bb = m0 >> 11, ll = (m0 & (L - 1)) + row;
    const int h0 = (n0 >> 6) + half;
    size_t dbase = ((size_t)(bb * H + h0) * L + ll) * HD;
#pragma unroll
    for (int c = 0; c < 8; ++c) {
      uint4 u = *(const uint4*)&smem[row * 136 + half * 64 + c * 8];
      *(uint4*)&dst[dbase + c * 8] = u;
    }
  }
}

// ---------------- flash attention (transposed QK, register P, dbuf) -----
// grid 512 XCD-swizzled (R7-proven); block 256 = 4 waves x 32 q-rows.
// QK^T computed transposed (S^T C-layout: qrow=lm, key=4lq+r). The K=16
// MFMA's A-layout (m=lane&15, k=quad*4+j) EQUALS that C-layout, so packed
// P feeds O=P@V directly from registers -- no P LDS round-trip (the R7
// per-iter serial chain). V B-frags are b64 reads from swizzled VTs.
__global__ __launch_bounds__(256) void attn_kernel(
    const unsigned short* __restrict__ q_hm, const unsigned short* __restrict__ k_hm,
    const unsigned short* __restrict__ vT, const unsigned char* __restrict__ mask,
    unsigned short* __restrict__ ctx) {
  __shared__ unsigned short Ksb[2 * 64 * 64];   // [buf][key][feat] swizzled
  __shared__ unsigned short Vtb[2 * 64 * 64];   // [buf][feat][key] swizzled
  __shared__ unsigned short Ps[128 * 72];       // Q staging overlay + epilogue
  const int bx = blockIdx.x;
  const int rest = bx >> 3;
  const int bhid = (bx & 7) + 8 * (rest >> 4);
  const int q0 = (rest & 15) * 128;
  const int h = bhid & 15, b = bhid >> 4;
  const size_t bh = (size_t)(b * H + h);
  const unsigned short* qp = q_hm + bh * L * HD;
  const unsigned short* kp = k_hm + bh * L * HD;
  const unsigned short* vp = vT + bh * HD * L;
  const int t = threadIdx.x, l = t & 63, w = t >> 6;
  const int lm = l & 15, lq = l >> 4;
  const int fsw = ((t & 7) ^ ((t >> 3) & 7)) * 8;
  const int swm = lm & 7;
  const int srow = t >> 3;

  unsigned short* Qs = Ps;
#pragma unroll
  for (int c = 0; c < 4; ++c) {
    int row = 32 * c + srow;
    gload_lds16(&qp[(size_t)(q0 + row) * HD + fsw], &Qs[(32 * c + 8 * w) * 64]);
  }
#pragma unroll
  for (int c = 0; c < 2; ++c) {
    int row = 32 * c + srow;
    gload_lds16(&kp[(size_t)row * HD + fsw], &Ksb[(32 * c + 8 * w) * 64]);
    gload_lds16(&vp[(size_t)row * L + fsw], &Vtb[(32 * c + 8 * w) * 64]);
  }
  __syncthreads();
  bf16x8 qf[2][2];
#pragma unroll
  for (int i = 0; i < 2; ++i)
#pragma unroll
    for (int kk = 0; kk < 2; ++kk)
      qf[i][kk] = *(const bf16x8*)&Qs[(w * 32 + 16 * i + lm) * 64 + ((kk * 4 + lq) ^ swm) * 8];

  float lsum[2] = {0.f, 0.f};
  f32x4 ot[2][4] = {};   // HAVE_MFMA16: O[qrow=4lq+r][feat=16jf+lm]; else O^T

  for (int kt = 0; kt < L / 64; ++kt) {
    const int cur = kt & 1;
    const unsigned short* Kc = Ksb + cur * (64 * 64);
    const unsigned short* Vc = Vtb + cur * (64 * 64);
    if (kt + 1 < L / 64) {
      const int nk0 = (kt + 1) * 64;
      unsigned short* Kd = Ksb + (cur ^ 1) * (64 * 64);
      unsigned short* Vd = Vtb + (cur ^ 1) * (64 * 64);
#pragma unroll
      for (int c = 0; c < 2; ++c) {
        int row = 32 * c + srow;
        gload_lds16(&kp[(size_t)(nk0 + row) * HD + fsw], &Kd[(32 * c + 8 * w) * 64]);
        gload_lds16(&vp[(size_t)row * L + nk0 + fsw], &Vd[(32 * c + 8 * w) * 64]);
      }
    }
    unsigned long long mb = __ballot(mask[b * L + kt * 64 + l] != 0);

    // S^T tiles: st[jt][i], key = 16*jt + 4*lq + r, qrow = w*32 + 16*i + lm
    f32x4 st[4][2];
#pragma unroll
    for (int jt = 0; jt < 4; ++jt) {
      bf16x8 kf[2];
#pragma unroll
      for (int kk = 0; kk < 2; ++kk)
        kf[kk] = *(const bf16x8*)&Kc[(16 * jt + lm) * 64 + ((kk * 4 + lq) ^ swm) * 8];
#pragma unroll
      for (int i = 0; i < 2; ++i) {
        f32x4 a = {};
        a = __builtin_amdgcn_mfma_f32_16x16x32_bf16(kf[0], qf[i][0], a, 0, 0, 0);
        a = __builtin_amdgcn_mfma_f32_16x16x32_bf16(kf[1], qf[i][1], a, 0, 0, 0);
        st[jt][i] = a;
      }
    }
    if (mb) {  // wave-uniform; test mask is all-false so this is skipped
      unsigned mlo = (unsigned)(mb >> (4 * lq));
      unsigned mhi = (unsigned)(mb >> (4 * lq + 32));
#pragma unroll
      for (int jt = 0; jt < 4; ++jt)
#pragma unroll
        for (int i = 0; i < 2; ++i)
#pragma unroll
          for (int r = 0; r < 4; ++r) {
            unsigned bits = jt < 2 ? mlo : mhi;
            if ((bits >> (16 * (jt & 1) + r)) & 1u) st[jt][i][r] = -1e30f;
          }
    }
    // p = exp2(s) raw, accumulate lsum; pack P for register-direct PV
#if HAVE_MFMA16
    union { uint2 u; bf16x4 v; } pp[2][4];
#endif
#pragma unroll
    for (int i = 0; i < 2; ++i) {
      float ps = 0.f;
#pragma unroll
      for (int jt = 0; jt < 4; ++jt) {
        f32x4 p;
#pragma unroll
        for (int r = 0; r < 4; ++r) {
          float e = __builtin_amdgcn_exp2f(st[jt][i][r]);
          p[r] = e;
          ps += e;
        }
#if HAVE_MFMA16
        pp[i][jt].u.x = pack2bf_trunc(p[0], p[1]);
        pp[i][jt].u.y = pack2bf_trunc(p[2], p[3]);
#else
        uint2 u;
        u.x = pack2bf_trunc(p[0], p[1]);
        u.y = pack2bf_trunc(p[2], p[3]);
        *(uint2*)&Ps[(w * 32 + 16 * i + lm) * 72 + 16 * jt + 4 * lq] = u;
#endif
      }
      lsum[i] += ps;
    }
#if HAVE_MFMA16
    // O += P @ V, K=16 chunks: A = pp (C-layout == A-layout), B = V^T b64
#pragma unroll
    for (int jf = 0; jf < 4; ++jf) {
#pragma unroll
      for (int kc = 0; kc < 4; ++kc) {
        int chunk = (2 * kc + (lq >> 1)) ^ swm;
        bf16x4 vb = *(const bf16x4*)&Vc[(16 * jf + lm) * 64 + chunk * 8 + 4 * (lq & 1)];
#pragma unroll
        for (int i = 0; i < 2; ++i)
          ot[i][jf] = __builtin_amdgcn_mfma_f32_16x16x16bf16_1k(
              pp[i][kc].v, vb, ot[i][jf], 0, 0, 0);
      }
    }
#else
    // O^T += V^T P^T (R7 fallback)
    bf16x8 pf[2][2];
#pragma unroll
    for (int i = 0; i < 2; ++i)
#pragma unroll
      for (int kk = 0; kk < 2; ++kk)
        pf[i][kk] = *(const bf16x8*)&Ps[(w * 32 + 16 * i + lm) * 72 + kk * 32 + lq * 8];
#pragma unroll
    for (int jf = 0; jf < 4; ++jf) {
      bf16x8 vf[2];
#pragma unroll
      for (int kk = 0; kk < 2; ++kk)
        vf[kk] = *(const bf16x8*)&Vc[(16 * jf + lm) * 64 + ((kk * 4 + lq) ^ swm) * 8];
#pragma unroll
      for (int i = 0; i < 2; ++i) {
        ot[i][jf] = __builtin_amdgcn_mfma_f32_16x16x32_bf16(vf[0], pf[i][0], ot[i][jf], 0, 0, 0);
        ot[i][jf] = __builtin_amdgcn_mfma_f32_16x16x32_bf16(vf[1], pf[i][1], ot[i][jf], 0, 0, 0);
      }
    }
#endif
    __syncthreads();
  }

  // lsum totals (per lane: qrow = 16i + lm)
  float rl[2];
#pragma unroll
  for (int i = 0; i < 2; ++i) {
    float s = lsum[i];
    s += __shfl_xor(s, 16, 64);
    s += __shfl_xor(s, 32, 64);
    rl[i] = 1.0f / s;
  }

#if HAVE_MFMA16
  // O is [qrow=32w+16i+4lq+r][feat=16jf+lm]; gather rl for row 4lq+r, write
  // rows to Ps (stride 72), then coalesced 16B stores (wave-private rows).
#pragma unroll
  for (int i = 0; i < 2; ++i) {
    float rlq[4];
#pragma unroll
    for (int r = 0; r < 4; ++r) rlq[r] = __shfl(rl[i], 4 * lq + r, 64);
#pragma unroll
    for (int jf = 0; jf < 4; ++jf)
#pragma unroll
      for (int r = 0; r < 4; ++r)
        Ps[(w * 32 + 16 * i + 4 * lq + r) * 72 + 16 * jf + lm] =
            f2bf(ot[i][jf][r] * rlq[r]);
  }
#else
  // O^T: transpose through Ps as in R7
#pragma unroll
  for (int i = 0; i < 2; ++i)
#pragma unroll
    for (int jf = 0; jf < 4; ++jf) {
      uint2 u;
      u.x = pack2bf(ot[i][jf][0] * rl[i], ot[i][jf][1] * rl[i]);
      u.y = pack2bf(ot[i][jf][2] * rl[i], ot[i][jf][3] * rl[i]);
      *(uint2*)&Ps[(w * 32 + 16 * i + lm) * 72 + 16 * jf + 4 * lq] = u;
    }
#endif
  {
    int row = l >> 1, half = l & 1;
    size_t obase = ((size_t)(b * L + q0 + w * 32 + row)) * D + h * HD + half * 32;
#pragma unroll
    for (int c = 0; c < 4; ++c) {
      uint4 u = *(const uint4*)&Ps[(w * 32 + row) * 72 + half * 32 + c * 8];
      *(uint4*)&ctx[obase + c * 8] = u;
    }
  }
}

// ---------------- output projection GEMM (BK=64): out = ctx@Wo + bo ------
__global__ __launch_bounds__(256) void outgemm_kernel(
    const unsigned short* __restrict__ ctx, const unsigned short* __restrict__ WoT,
    const float* __restrict__ bo, float* __restrict__ out) {
  __shared__ unsigned short As[64 * 64];    // 8 KB
  __shared__ unsigned short Bs[128 * 64];   // 16 KB
  const int m0 = blockIdx.y * 64, n0 = blockIdx.x * 128;
  const int t = threadIdx.x, l = t & 63, w = t >> 6;
  const int wm = w >> 1, wn = w & 1;
  const int lm = l & 15, lq = l >> 4;
  const int srow8 = t >> 3;
  const int fsw = ((t & 7) ^ ((t >> 3) & 7)) * 8;
  const int swm = lm & 7;
  f32x4 acc[2][4] = {};
  for (int kt = 0; kt < D / 64; ++kt) {
    const int kb = kt * 64;
#pragma unroll
    for (int c = 0; c < 2; ++c)
      gload_lds16(&ctx[(size_t)(m0 + 32 * c + srow8) * D + kb + fsw],
                  &As[(32 * c + 8 * w) * 64]);
#pragma unroll
    for (int c = 0; c < 4; ++c)
      gload_lds16(&WoT[(size_t)(n0 + 32 * c + srow8) * D + kb + fsw],
                  &Bs[(32 * c + 8 * w) * 64]);
    __syncthreads();
#pragma unroll
    for (int kk = 0; kk < 2; ++kk) {
      bf16x8 af[2], bf[4];
#pragma unroll
      for (int i = 0; i < 2; ++i)
        af[i] = *(const bf16x8*)&As[(32 * wm + 16 * i + lm) * 64 + ((kk * 4 + lq) ^ swm) * 8];
#pragma unroll
      for (int j = 0; j < 4; ++j)
        bf[j] = *(const bf16x8*)&Bs[(64 * wn + 16 * j + lm) * 64 + ((kk * 4 + lq) ^ swm) * 8];
#pragma unroll
      for (int i = 0; i < 2; ++i)
#pragma unroll
        for (int j = 0; j < 4; ++j)
          acc[i][j] = __builtin_amdgcn_mfma_f32_16x16x32_bf16(af[i], bf[j], acc[i][j], 0, 0, 0);
    }
    __syncthreads();
  }
#pragma unroll
  for (int i = 0; i < 2; ++i)
#pragma unroll
    for (int j = 0; j < 4; ++j)
#pragma unroll
      for (int r = 0; r < 4; ++r) {
        int grow = m0 + 32 * wm + 16 * i + lq * 4 + r;
        int gcol = n0 + 64 * wn + 16 * j + lm;
        out[(size_t)grow * D + gcol] = acc[i][j][r] + bo[gcol];
      }
}

extern "C" void kernel_launch(void* const* d_in, const int* in_sizes, int n_in,
                              void* d_out, int out_size, void* d_ws, size_t ws_size,
                              hipStream_t stream) {
  const float* x    = (const float*)d_in[0];
  const float* subj = (const float*)d_in[1];
  const unsigned char* mask = (const unsigned char*)d_in[2];
  const float* Wq = (const float*)d_in[3];
  const float* Wk = (const float*)d_in[4];
  const float* Wv = (const float*)d_in[5];
  const float* Wo = (const float*)d_in[6];
  const float* bo = (const float*)d_in[7];
  const float* Wsq = (const float*)d_in[8];
  const float* bsq = (const float*)d_in[9];
  const float* Wsk = (const float*)d_in[10];
  const float* bsk = (const float*)d_in[11];
  float* out = (float*)d_out;
  char* ws = (char*)d_ws;

  // workspace layout (bytes)
  unsigned short* xb  = (unsigned short*)(ws);                    // 8 MB
  unsigned short* WT4 = (unsigned short*)(ws + (8ull  << 20));    // 8 MB
  unsigned short* qk  = (unsigned short*)(ws + (16ull << 20));    // 16 MB (q,k)
  unsigned short* ctx = (unsigned short*)(ws + (32ull << 20));    // 8 MB
  unsigned short* vT  = (unsigned short*)(ws + (40ull << 20));    // 8 MB
  float* sq = (float*)(ws + (48ull << 20));                       // 8 KB
  float* sk = sq + B * D;

  hipLaunchKernelGGL(prep_kernel, dim3(3088), dim3(256), 0, stream,
                     Wq, Wk, Wv, Wo, x, subj, Wsq, bsq, Wsk, bsk, WT4, xb, sq, sk);
  hipLaunchKernelGGL(proj_kernel, dim3(8, 32, 3), dim3(256), 0, stream,
                     xb, WT4, sq, sk, qk, vT);
  hipLaunchKernelGGL(attn_kernel, dim3(512), dim3(256), 0, stream,
                     qk, qk + (size_t)M * D, vT, mask, ctx);
  hipLaunchKernelGGL(outgemm_kernel, dim3(8, 64, 1), dim3(256), 0, stream, ctx,
                     WT4 + 3ull * D * D, bo, out);
}

// Round 10
// 214.343 us; speedup vs baseline: 1.0650x; 1.0289x over previous
//
#include <hip/hip_runtime.h>
#include <hip/hip_bf16.h>
#include <math.h>

#define DEV __device__ __forceinline__

typedef short bf16x8 __attribute__((ext_vector_type(8)));
typedef short bf16x4 __attribute__((ext_vector_type(4)));
typedef float f32x4 __attribute__((ext_vector_type(4)));

static constexpr int D  = 1024;
static constexpr int H  = 16;
static constexpr int HD = 64;
static constexpr int DS = 64;
static constexpr int B  = 2;
static constexpr int L  = 2048;
static constexpr int M  = B * L;   // 4096

// softmax scale * log2(e), folded into q at projection time (exp2-based
// softmax, no max subtraction: scores bounded far below exp2 overflow;
// masked scores (-1e30) give exp2 -> 0 exactly).
static constexpr float QSCALE = 0.18033688011112042f; // 0.125 * log2(e)

DEV unsigned short f2bf(float f) {
  union { float f; unsigned u; } x; x.f = f;
  unsigned r = (x.u + 0x7FFFu + ((x.u >> 16) & 1u)) >> 16;
  return (unsigned short)r;
}

DEV unsigned pack2bf(float a, float b) {
  return (unsigned)f2bf(a) | ((unsigned)f2bf(b) << 16);
}

// truncation pack (P only: truncation bias cancels between Sum(p*v) and Sum(p))
DEV unsigned pack2bf_trunc(float a, float b) {
  union { float f; unsigned u; } ua{a}, ub{b};
  return (ua.u >> 16) | (ub.u & 0xffff0000u);
}

// async global->LDS, 16B per lane; LDS dest = wave-uniform base + 16*lane.
DEV void gload_lds16(const void* g, void* l) {
  __builtin_amdgcn_global_load_lds(
      (const __attribute__((address_space(1))) unsigned int*)g,
      (__attribute__((address_space(3))) unsigned int*)l, 16, 0, 0);
}

// ---------------- merged preprocessing ----------------
// blocks [0,1024): W transpose+bf16; [1024,3072): x->bf16; [3072,3088): sq/sk
__global__ __launch_bounds__(256) void prep_kernel(
    const float* __restrict__ Wq, const float* __restrict__ Wk,
    const float* __restrict__ Wv, const float* __restrict__ Wo,
    const float* __restrict__ x, const float* __restrict__ subj,
    const float* __restrict__ Wsq, const float* __restrict__ bsq,
    const float* __restrict__ Wsk, const float* __restrict__ bsk,
    unsigned short* __restrict__ WT4, unsigned short* __restrict__ xb,
    float* __restrict__ sq, float* __restrict__ sk) {
  __shared__ float tile[64][65];
  const int blk = blockIdx.x, t = threadIdx.x;
  if (blk < 1024) {
    const int z = blk >> 8, idx = blk & 255;
    const float* W = z == 0 ? Wq : z == 1 ? Wk : z == 2 ? Wv : Wo;
    unsigned short* dst = WT4 + (size_t)z * D * D;
    const int n0 = (idx & 15) * 64, k0 = (idx >> 4) * 64;
    const int c = t & 63, r4 = t >> 6;
#pragma unroll
    for (int rr = 0; rr < 16; ++rr) {
      int row = r4 + rr * 4;
      tile[row][c] = W[(size_t)(k0 + row) * D + n0 + c];
    }
    __syncthreads();
#pragma unroll
    for (int rr = 0; rr < 16; ++rr) {
      int nrow = r4 + rr * 4;
      dst[(size_t)(n0 + nrow) * D + k0 + c] = f2bf(tile[c][nrow]);
    }
  } else if (blk < 3072) {
    size_t g = (size_t)(blk - 1024) * 256 + t;
    const float4* xf = (const float4*)x;
    float4 a = xf[2 * g], b = xf[2 * g + 1];
    union { unsigned short s[8]; uint4 v; } o;
    o.s[0] = f2bf(a.x); o.s[1] = f2bf(a.y); o.s[2] = f2bf(a.z); o.s[3] = f2bf(a.w);
    o.s[4] = f2bf(b.x); o.s[5] = f2bf(b.y); o.s[6] = f2bf(b.z); o.s[7] = f2bf(b.w);
    ((uint4*)xb)[g] = o.v;
  } else {
    int g = (blk - 3072) * 256 + t;  // [0, 4096)
    int ty = g >> 11, b = (g >> 10) & 1, n = g & 1023;
    const float* W = ty ? Wsk : Wsq;
    const float* bias = ty ? bsk : bsq;
    float s = bias[n];
#pragma unroll 8
    for (int d = 0; d < DS; ++d) s += subj[b * DS + d] * W[d * D + n];
    (ty ? sk : sq)[b * D + n] = s;
  }
}

// ---------------- fused QKV projection GEMM (BK=64) ----------------
// z=0: q = (x@Wq + sq)*QSCALE -> qk[0]; z=1: k = x@Wk + sk -> qk[1]
// z=2: v = x@Wv written directly transposed to vT[B,H,64,L] (fused vtrans).
__global__ __launch_bounds__(256) void proj_kernel(
    const unsigned short* __restrict__ xb, const unsigned short* __restrict__ WT3,
    const float* __restrict__ sq, const float* __restrict__ sk,
    unsigned short* __restrict__ qk, unsigned short* __restrict__ vT) {
  __shared__ __align__(16) unsigned short smem[128 * 136];  // 34.8 KB
  unsigned short* As = smem;             // 128*64 (16 KB)
  unsigned short* Bs = smem + 128 * 64;  // 128*64 (16 KB)
  const int z = blockIdx.z;
  const unsigned short* Wt = WT3 + (size_t)z * D * D;
  const int m0 = blockIdx.y * 128, n0 = blockIdx.x * 128;
  const int t = threadIdx.x, l = t & 63, w = t >> 6;
  const int wm = w >> 1, wn = w & 1;
  const int lm = l & 15, lq = l >> 4;
  const int srow8 = t >> 3;
  const int fsw = ((t & 7) ^ ((t >> 3) & 7)) * 8;
  const int swm = lm & 7;
  f32x4 acc[4][4] = {};
  for (int kt = 0; kt < D / 64; ++kt) {
    const int kb = kt * 64;
#pragma unroll
    for (int c = 0; c < 4; ++c) {
      int row = 32 * c + srow8;
      gload_lds16(&xb[(size_t)(m0 + row) * D + kb + fsw], &As[(32 * c + 8 * w) * 64]);
      gload_lds16(&Wt[(size_t)(n0 + row) * D + kb + fsw], &Bs[(32 * c + 8 * w) * 64]);
    }
    __syncthreads();
#pragma unroll
    for (int kk = 0; kk < 2; ++kk) {
      bf16x8 af[4], bf[4];
#pragma unroll
      for (int i = 0; i < 4; ++i)
        af[i] = *(const bf16x8*)&As[(64 * wm + 16 * i + lm) * 64 + ((kk * 4 + lq) ^ swm) * 8];
#pragma unroll
      for (int j = 0; j < 4; ++j)
        bf[j] = *(const bf16x8*)&Bs[(64 * wn + 16 * j + lm) * 64 + ((kk * 4 + lq) ^ swm) * 8];
#pragma unroll
      for (int i = 0; i < 4; ++i)
#pragma unroll
        for (int j = 0; j < 4; ++j)
          acc[i][j] = __builtin_amdgcn_mfma_f32_16x16x32_bf16(af[i], bf[j], acc[i][j], 0, 0, 0);
    }
    __syncthreads();
  }
  if (z == 2) {
    // transpose epilogue: acc -> smem T[col][row] (stride 136) -> vT
#pragma unroll
    for (int i = 0; i < 4; ++i)
#pragma unroll
      for (int j = 0; j < 4; ++j) {
        int cr = 64 * wn + 16 * j + lm;
        int rr = 64 * wm + 16 * i + 4 * lq;
        uint2 u;
        u.x = pack2bf(acc[i][j][0], acc[i][j][1]);
        u.y = pack2bf(acc[i][j][2], acc[i][j][3]);
        *(uint2*)&smem[cr * 136 + rr] = u;
      }
    __syncthreads();
    const int cr = t >> 1, half = t & 1;
    const int bb = m0 >> 11, l0 = m0 & (L - 1);
    const int gcol = n0 + cr, h = gcol >> 6, hd = gcol & 63;
    size_t dbase = ((size_t)(bb * H + h) * HD + hd) * L + l0 + half * 64;
#pragma unroll
    for (int c = 0; c < 8; ++c) {
      uint4 u = *(const uint4*)&smem[cr * 136 + half * 64 + c * 8];
      *(uint4*)&vT[dbase + c * 8] = u;
    }
  } else {
    unsigned short* dst = qk + (size_t)z * M * D;
    const float* bias = z == 0 ? sq : sk;
    const float post = z == 0 ? QSCALE : 1.0f;
    // stage [row][col] into smem, then fully-coalesced 16B stores
#pragma unroll
    for (int i = 0; i < 4; ++i)
#pragma unroll
      for (int j = 0; j < 4; ++j)
#pragma unroll
        for (int r = 0; r < 4; ++r) {
          int rr = 64 * wm + 16 * i + 4 * lq + r;
          int cc = 64 * wn + 16 * j + lm;
          float v = (acc[i][j][r] + bias[((m0 + rr) >> 11) * D + n0 + cc]) * post;
          smem[rr * 136 + cc] = f2bf(v);
        }
    __syncthreads();
    const int row = t >> 1, half = t & 1;
    const int bb = m0 >> 11, ll = (m0 & (L - 1)) + row;
    const int h0 = (n0 >> 6) + half;
    size_t dbase = ((size_t)(bb * H + h0) * L + ll) * HD;
#pragma unroll
    for (int c = 0; c < 8; ++c) {
      uint4 u = *(const uint4*)&smem[row * 136 + half * 64 + c * 8];
      *(uint4*)&dst[dbase + c * 8] = u;
    }
  }
}

// ---------------- flash attention (BK=128, register P, dbuf) ----------
// grid 512 XCD-swizzled; block 256 = 4 waves x 32 q-rows.
// 16 iterations of 128 keys (half the barrier drains of BK=64); per iter,
// 8 independent jt chains (QK -> exp2 -> PV fused per 16-key group).
// Mask bytes are loaded BEFORE the prefetch DMAs so the ballot's vmcnt wait
// does not drain the prefetch (FIFO vmcnt: mask loads are the oldest).
__global__ __launch_bounds__(256) void attn_kernel(
    const unsigned short* __restrict__ q_hm, const unsigned short* __restrict__ k_hm,
    const unsigned short* __restrict__ vT, const unsigned char* __restrict__ mask,
    unsigned short* __restrict__ ctx) {
  __shared__ unsigned short Qs[128 * 64];       // 16 KB
  __shared__ unsigned short Ksb[2 * 128 * 64];  // 32 KB [buf][key][feat]
  __shared__ unsigned short Vtb[2 * 64 * 128];  // 32 KB [buf][feat][key]
  const int bx = blockIdx.x;
  const int rest = bx >> 3;
  const int bhid = (bx & 7) + 8 * (rest >> 4);
  const int q0 = (rest & 15) * 128;
  const int h = bhid & 15, b = bhid >> 4;
  const size_t bh = (size_t)(b * H + h);
  const unsigned short* qp = q_hm + bh * L * HD;
  const unsigned short* kp = k_hm + bh * L * HD;
  const unsigned short* vp = vT + bh * HD * L;
  const int t = threadIdx.x, l = t & 63, w = t >> 6;
  const int lm = l & 15, lq = l >> 4;
  const int fsw = ((t & 7) ^ ((t >> 3) & 7)) * 8;  // 8-chunk swizzle (64-wide rows)
  const int swm = lm & 7;
  const int srow = t >> 3;                         // 0..31
  const int vs = t & 15, vr = t >> 4;              // V staging: slot, row
  const int vcsrc = ((vs & 8) | ((vs & 7) ^ (vr & 7))) * 8;  // 16-chunk swizzle

  // stage Q + first K/V tile
#pragma unroll
  for (int c = 0; c < 4; ++c) {
    gload_lds16(&qp[(size_t)(q0 + 32 * c + srow) * HD + fsw], &Qs[(32 * c + 8 * w) * 64]);
    gload_lds16(&kp[(size_t)(32 * c + srow) * HD + fsw], &Ksb[(32 * c + 8 * w) * 64]);
    gload_lds16(&vp[(size_t)(16 * c + vr) * L + vcsrc], &Vtb[(16 * c + 4 * w) * 128]);
  }
  __syncthreads();
  bf16x8 qf[2][2];
#pragma unroll
  for (int i = 0; i < 2; ++i)
#pragma unroll
    for (int kk = 0; kk < 2; ++kk)
      qf[i][kk] = *(const bf16x8*)&Qs[(w * 32 + 16 * i + lm) * 64 + ((kk * 4 + lq) ^ swm) * 8];

  float lsum[2] = {0.f, 0.f};
  f32x4 ot[2][4] = {};   // O[qrow=32w+16i+4lq+r][feat=16jf+lm]

  for (int kt = 0; kt < L / 128; ++kt) {
    const int cur = kt & 1;
    const unsigned short* Kc = Ksb + cur * (128 * 64);
    const unsigned short* Vc = Vtb + cur * (64 * 128);
    // mask bytes FIRST (oldest vmcnt entries)
    unsigned char mby0 = mask[b * L + kt * 128 + l];
    unsigned char mby1 = mask[b * L + kt * 128 + 64 + l];
    if (kt + 1 < L / 128) {
      const int nk0 = (kt + 1) * 128;
      unsigned short* Kd = Ksb + (cur ^ 1) * (128 * 64);
      unsigned short* Vd = Vtb + (cur ^ 1) * (64 * 128);
#pragma unroll
      for (int c = 0; c < 4; ++c) {
        gload_lds16(&kp[(size_t)(nk0 + 32 * c + srow) * HD + fsw], &Kd[(32 * c + 8 * w) * 64]);
        gload_lds16(&vp[(size_t)(16 * c + vr) * L + nk0 + vcsrc], &Vd[(16 * c + 4 * w) * 128]);
      }
    }
    unsigned long long mb0 = __ballot(mby0 != 0);
    unsigned long long mb1 = __ballot(mby1 != 0);

#pragma unroll
    for (int jt = 0; jt < 8; ++jt) {
      // S^T for this 16-key group: key = 16*jt + 4*lq + r, qrow = 16*i + lm
      bf16x8 kf0 = *(const bf16x8*)&Kc[(16 * jt + lm) * 64 + ((0 + lq) ^ swm) * 8];
      bf16x8 kf1 = *(const bf16x8*)&Kc[(16 * jt + lm) * 64 + ((4 + lq) ^ swm) * 8];
      f32x4 st[2];
#pragma unroll
      for (int i = 0; i < 2; ++i) {
        f32x4 a = {};
        a = __builtin_amdgcn_mfma_f32_16x16x32_bf16(kf0, qf[i][0], a, 0, 0, 0);
        a = __builtin_amdgcn_mfma_f32_16x16x32_bf16(kf1, qf[i][1], a, 0, 0, 0);
        st[i] = a;
      }
      unsigned long long mbX = jt < 4 ? mb0 : mb1;
      if (mbX) {  // wave-uniform; all-false mask skips this
        int jm = jt & 3;
        unsigned bits = (unsigned)(mbX >> (4 * lq + 16 * jm));
#pragma unroll
        for (int i = 0; i < 2; ++i)
#pragma unroll
          for (int r = 0; r < 4; ++r)
            if ((bits >> r) & 1u) st[i][r] = -1e30f;
      }
      // p = exp2(s); pack to A-operand layout (C-layout == K=16 A-layout)
      union { uint2 u; bf16x4 v; } pp[2];
#pragma unroll
      for (int i = 0; i < 2; ++i) {
        f32x4 p;
        float ps = 0.f;
#pragma unroll
        for (int r = 0; r < 4; ++r) {
          float e = __builtin_amdgcn_exp2f(st[i][r]);
          p[r] = e;
          ps += e;
        }
        lsum[i] += ps;
        pp[i].u.x = pack2bf_trunc(p[0], p[1]);
        pp[i].u.y = pack2bf_trunc(p[2], p[3]);
      }
      // O += P@V for this key group (register-direct A; V^T b64 reads)
      const int kc2 = 2 * jt + (lq >> 1);
      const int slot = (kc2 & 8) | ((kc2 & 7) ^ swm);
#pragma unroll
      for (int jf = 0; jf < 4; ++jf) {
        bf16x4 vb = *(const bf16x4*)&Vc[(16 * jf + lm) * 128 + slot * 8 + 4 * (lq & 1)];
#pragma unroll
        for (int i = 0; i < 2; ++i)
          ot[i][jf] = __builtin_amdgcn_mfma_f32_16x16x16bf16_1k(
              pp[i].v, vb, ot[i][jf], 0, 0, 0);
      }
    }
    __syncthreads();
  }

  // lsum totals (valid per lane for qrow = 16i + lm)
  float rl[2];
#pragma unroll
  for (int i = 0; i < 2; ++i) {
    float s = lsum[i];
    s += __shfl_xor(s, 16, 64);
    s += __shfl_xor(s, 32, 64);
    rl[i] = 1.0f / s;
  }

  // epilogue: O rows -> Es (= Ksb reuse, stride 72) -> coalesced 16B stores.
  // Safe: final loop barrier done; each wave touches only its own 32 rows.
  unsigned short* Es = Ksb;
#pragma unroll
  for (int i = 0; i < 2; ++i) {
    float rlq[4];
#pragma unroll
    for (int r = 0; r < 4; ++r) rlq[r] = __shfl(rl[i], 4 * lq + r, 64);
#pragma unroll
    for (int jf = 0; jf < 4; ++jf)
#pragma unroll
      for (int r = 0; r < 4; ++r)
        Es[(w * 32 + 16 * i + 4 * lq + r) * 72 + 16 * jf + lm] =
            f2bf(ot[i][jf][r] * rlq[r]);
  }
  {
    int row = l >> 1, half = l & 1;
    size_t obase = ((size_t)(b * L + q0 + w * 32 + row)) * D + h * HD + half * 32;
#pragma unroll
    for (int c = 0; c < 4; ++c) {
      uint4 u = *(const uint4*)&Es[(w * 32 + row) * 72 + half * 32 + c * 8];
      *(uint4*)&ctx[obase + c * 8] = u;
    }
  }
}

// ---------------- output projection GEMM (BK=64): out = ctx@Wo + bo ------
__global__ __launch_bounds__(256) void outgemm_kernel(
    const unsigned short* __restrict__ ctx, const unsigned short* __restrict__ WoT,
    const float* __restrict__ bo, float* __restrict__ out) {
  __shared__ unsigned short As[64 * 64];    // 8 KB
  __shared__ unsigned short Bs[128 * 64];   // 16 KB
  const int m0 = blockIdx.y * 64, n0 = blockIdx.x * 128;
  const int t = threadIdx.x, l = t & 63, w = t >> 6;
  const int wm = w >> 1, wn = w & 1;
  const int lm = l & 15, lq = l >> 4;
  const int srow8 = t >> 3;
  const int fsw = ((t & 7) ^ ((t >> 3) & 7)) * 8;
  const int swm = lm & 7;
  f32x4 acc[2][4] = {};
  for (int kt = 0; kt < D / 64; ++kt) {
    const int kb = kt * 64;
#pragma unroll
    for (int c = 0; c < 2; ++c)
      gload_lds16(&ctx[(size_t)(m0 + 32 * c + srow8) * D + kb + fsw],
                  &As[(32 * c + 8 * w) * 64]);
#pragma unroll
    for (int c = 0; c < 4; ++c)
      gload_lds16(&WoT[(size_t)(n0 + 32 * c + srow8) * D + kb + fsw],
                  &Bs[(32 * c + 8 * w) * 64]);
    __syncthreads();
#pragma unroll
    for (int kk = 0; kk < 2; ++kk) {
      bf16x8 af[2], bf[4];
#pragma unroll
      for (int i = 0; i < 2; ++i)
        af[i] = *(const bf16x8*)&As[(32 * wm + 16 * i + lm) * 64 + ((kk * 4 + lq) ^ swm) * 8];
#pragma unroll
      for (int j = 0; j < 4; ++j)
        bf[j] = *(const bf16x8*)&Bs[(64 * wn + 16 * j + lm) * 64 + ((kk * 4 + lq) ^ swm) * 8];
#pragma unroll
      for (int i = 0; i < 2; ++i)
#pragma unroll
        for (int j = 0; j < 4; ++j)
          acc[i][j] = __builtin_amdgcn_mfma_f32_16x16x32_bf16(af[i], bf[j], acc[i][j], 0, 0, 0);
    }
    __syncthreads();
  }
#pragma unroll
  for (int i = 0; i < 2; ++i)
#pragma unroll
    for (int j = 0; j < 4; ++j)
#pragma unroll
      for (int r = 0; r < 4; ++r) {
        int grow = m0 + 32 * wm + 16 * i + lq * 4 + r;
        int gcol = n0 + 64 * wn + 16 * j + lm;
        out[(size_t)grow * D + gcol] = acc[i][j][r] + bo[gcol];
      }
}

extern "C" void kernel_launch(void* const* d_in, const int* in_sizes, int n_in,
                              void* d_out, int out_size, void* d_ws, size_t ws_size,
                              hipStream_t stream) {
  const float* x    = (const float*)d_in[0];
  const float* subj = (const float*)d_in[1];
  const unsigned char* mask = (const unsigned char*)d_in[2];
  const float* Wq = (const float*)d_in[3];
  const float* Wk = (const float*)d_in[4];
  const float* Wv = (const float*)d_in[5];
  const float* Wo = (const float*)d_in[6];
  const float* bo = (const float*)d_in[7];
  const float* Wsq = (const float*)d_in[8];
  const float* bsq = (const float*)d_in[9];
  const float* Wsk = (const float*)d_in[10];
  const float* bsk = (const float*)d_in[11];
  float* out = (float*)d_out;
  char* ws = (char*)d_ws;

  // workspace layout (bytes)
  unsigned short* xb  = (unsigned short*)(ws);                    // 8 MB
  unsigned short* WT4 = (unsigned short*)(ws + (8ull  << 20));    // 8 MB
  unsigned short* qk  = (unsigned short*)(ws + (16ull << 20));    // 16 MB (q,k)
  unsigned short* ctx = (unsigned short*)(ws + (32ull << 20));    // 8 MB
  unsigned short* vT  = (unsigned short*)(ws + (40ull << 20));    // 8 MB
  float* sq = (float*)(ws + (48ull << 20));                       // 8 KB
  float* sk = sq + B * D;

  hipLaunchKernelGGL(prep_kernel, dim3(3088), dim3(256), 0, stream,
                     Wq, Wk, Wv, Wo, x, subj, Wsq, bsq, Wsk, bsk, WT4, xb, sq, sk);
  hipLaunchKernelGGL(proj_kernel, dim3(8, 32, 3), dim3(256), 0, stream,
                     xb, WT4, sq, sk, qk, vT);
  hipLaunchKernelGGL(attn_kernel, dim3(512), dim3(256), 0, stream,
                     qk, qk + (size_t)M * D, vT, mask, ctx);
  hipLaunchKernelGGL(outgemm_kernel, dim3(8, 64, 1), dim3(256), 0, stream, ctx,
                     WT4 + 3ull * D * D, bo, out);
}